// Round 5
// baseline (944.781 us; speedup 1.0000x reference)
//
#include <hip/hip_runtime.h>

// Causal depthwise FIR conv, 512 taps, fp32, software-pipelined.
// out[b,t,d] = sum_k filt[k,d] * X(t-k), X(m)=x[b,m,d] (m>=0) else last[512+m,d]
// v3: NT=16 so both ping-pong window+filter buffers fit in <=128 VGPR
//     -> 4 waves/SIMD occupancy for latency hiding (round-4 failure mode:
//        160+ live regs at NT=32 forced the compiler to de-pipeline).

constexpr int CLEN  = 512;
constexpr int SEQ   = 4096;
constexpr int DIM   = 1024;
constexpr int BATCH = 4;

constexpr int NT   = 16;           // output times per thread
constexpr int DCH  = 256;          // channels per block (= threads)
constexpr int NBLK = CLEN / NT;    // 32 K-chunks

// dst[i] = X(t0 + i - wb*NT) for this thread's channel
#define LOAD_BLK(dst, wb)                                         \
  _Pragma("unroll")                                               \
  for (int i = 0; i < NT; ++i) {                                  \
    int r = t0 + i - (wb)*NT;                                     \
    const float* base = (r >= 0) ? xd : ld;                       \
    dst[i] = base[(ptrdiff_t)r * DIM];                            \
  }

#define LOAD_FR(dst, kb)                                          \
  _Pragma("unroll")                                               \
  for (int j = 0; j < NT; ++j)                                    \
    dst[j] = fd[(size_t)((kb) + j) * DIM];

// Upper triangle: taps j vs outputs i>=j, uses resident hi block only.
#define UFMA(fr, hi)                                              \
  _Pragma("unroll")                                               \
  for (int j = 0; j < NT; ++j)                                    \
    _Pragma("unroll")                                             \
    for (int i = j; i < NT; ++i)                                  \
      acc[i] = fmaf(fr[j], hi[i - j], acc[i]);

// Lower triangle: outputs i<j, uses the freshly loaded lo block.
#define LFMA(fr, lo)                                              \
  _Pragma("unroll")                                               \
  for (int j = 1; j < NT; ++j)                                    \
    _Pragma("unroll")                                             \
    for (int i = 0; i < j; ++i)                                   \
      acc[i] = fmaf(fr[j], lo[NT + i - j], acc[i]);

__global__ __launch_bounds__(DCH, 4) void cconv_fir(
    const float* __restrict__ x,      // [BATCH][SEQ][DIM]
    const float* __restrict__ last,   // [CLEN][DIM]
    const float* __restrict__ filt,   // [CLEN][DIM]
    float* __restrict__ out)          // [BATCH][SEQ][DIM]
{
    // Bijective XCD-chunk swizzle: 4096 blocks, 8 XCDs -> 512 contiguous ids.
    // id layout: [dg(2) | b(2) | tt(8)] -> each XCD owns 2 (dg,b) streams with
    // SEQUENTIAL t-tiles, keeping the sliding x-window + filter L2-resident.
    int bid = blockIdx.x;
    int id  = (bid & 7) * (int)(gridDim.x >> 3) + (bid >> 3);

    int tt = id & (SEQ / NT - 1);          // t-tile 0..255
    int b  = (id >> 8) & (BATCH - 1);      // batch
    int dg = id >> 10;                     // d-group

    int d  = dg * DCH + threadIdx.x;
    int t0 = tt * NT;

    const float* xd = x + ((size_t)b * SEQ) * DIM + d;
    const float* ld = last + (size_t)CLEN * DIM + d;  // ld[r*DIM] valid for r in [-512,-1]
    const float* fd = filt + d;

    float acc[NT];
#pragma unroll
    for (int i = 0; i < NT; ++i) acc[i] = 0.f;

    float wA[NT], wB[NT], fA[NT], fB[NT];

    // Prologue: block 0 (hi of chunk 0) and its taps.
    LOAD_BLK(wA, 0)
    LOAD_FR(fA, 0)

#pragma unroll 1
    for (int wp = 0; wp < NBLK; wp += 2) {
        // ---- chunk wp: hi=wA, lo=wB ----
        LOAD_BLK(wB, wp + 1)                 // wp+1 <= 31: rows >= t0-496 >= -496, in range
        { int kb = (wp + 1) * NT; LOAD_FR(fB, kb) }   // kb <= 496, in range
        UFMA(fA, wA)                         // 136 FMAs hide wB/fB latency
        LFMA(fA, wB)
        // ---- chunk wp+1: hi=wB, lo=wA ----
        LOAD_BLK(wA, wp + 2)                 // block 32: rows >= t0-512 >= -512, edge-legal
        { int kb = (wp + 2) * NT;
          if (kb > CLEN - NT) kb = CLEN - NT;  // row 512 would be OOB; values unused
          LOAD_FR(fA, kb) }
        UFMA(fB, wB)
        LFMA(fB, wA)
    }

    float* ob = out + ((size_t)b * SEQ) * DIM + d;
#pragma unroll
    for (int i = 0; i < NT; ++i)
        ob[(size_t)(t0 + i) * DIM] = acc[i];
}

extern "C" void kernel_launch(void* const* d_in, const int* in_sizes, int n_in,
                              void* d_out, int out_size, void* d_ws, size_t ws_size,
                              hipStream_t stream) {
    const float* x    = (const float*)d_in[0];
    const float* last = (const float*)d_in[1];
    const float* filt = (const float*)d_in[2];
    float* out        = (float*)d_out;

    const int nblocks = BATCH * (DIM / DCH) * (SEQ / NT);  // 4*4*256 = 4096
    cconv_fir<<<dim3(nblocks), dim3(DCH), 0, stream>>>(x, last, filt, out);
}

// Round 6
// 426.673 us; speedup vs baseline: 2.2143x; 2.2143x over previous
//
#include <hip/hip_runtime.h>

// Causal depthwise FIR conv, 512 taps, fp32, software-pipelined.
// out[b,t,d] = sum_k filt[k,d] * X(t-k), X(m)=x[b,m,d] (m>=0) else last[512+m,d]
// v4: NT=16 ping-pong (fits in 128 VGPR) + __launch_bounds__(DCH,2).
//     Round-5 failure: (DCH,4) clamped VGPR to 64 -> massive scratch spill
//     (3.8 GB HBM traffic). (DCH,2) empirically allocates 128 VGPR, no spill,
//     and ~110 live regs still gives 4 waves/SIMD at runtime.

constexpr int CLEN  = 512;
constexpr int SEQ   = 4096;
constexpr int DIM   = 1024;
constexpr int BATCH = 4;

constexpr int NT   = 16;           // output times per thread
constexpr int DCH  = 256;          // channels per block (= threads)
constexpr int NBLK = CLEN / NT;    // 32 K-chunks

// dst[i] = X(t0 + i - wb*NT) for this thread's channel
#define LOAD_BLK(dst, wb)                                         \
  _Pragma("unroll")                                               \
  for (int i = 0; i < NT; ++i) {                                  \
    int r = t0 + i - (wb)*NT;                                     \
    const float* base = (r >= 0) ? xd : ld;                       \
    dst[i] = base[(ptrdiff_t)r * DIM];                            \
  }

#define LOAD_FR(dst, kb)                                          \
  _Pragma("unroll")                                               \
  for (int j = 0; j < NT; ++j)                                    \
    dst[j] = fd[(size_t)((kb) + j) * DIM];

// Upper triangle: taps j vs outputs i>=j, uses resident hi block only.
#define UFMA(fr, hi)                                              \
  _Pragma("unroll")                                               \
  for (int j = 0; j < NT; ++j)                                    \
    _Pragma("unroll")                                             \
    for (int i = j; i < NT; ++i)                                  \
      acc[i] = fmaf(fr[j], hi[i - j], acc[i]);

// Lower triangle: outputs i<j, uses the freshly loaded lo block.
#define LFMA(fr, lo)                                              \
  _Pragma("unroll")                                               \
  for (int j = 1; j < NT; ++j)                                    \
    _Pragma("unroll")                                             \
    for (int i = 0; i < j; ++i)                                   \
      acc[i] = fmaf(fr[j], lo[NT + i - j], acc[i]);

__global__ __launch_bounds__(DCH, 2) void cconv_fir(
    const float* __restrict__ x,      // [BATCH][SEQ][DIM]
    const float* __restrict__ last,   // [CLEN][DIM]
    const float* __restrict__ filt,   // [CLEN][DIM]
    float* __restrict__ out)          // [BATCH][SEQ][DIM]
{
    // Bijective XCD-chunk swizzle: 4096 blocks, 8 XCDs -> 512 contiguous ids.
    // id layout: [dg(2) | b(2) | tt(8)] -> each XCD owns 2 (dg,b) streams with
    // SEQUENTIAL t-tiles, keeping the sliding x-window + filter L2-resident.
    int bid = blockIdx.x;
    int id  = (bid & 7) * (int)(gridDim.x >> 3) + (bid >> 3);

    int tt = id & (SEQ / NT - 1);          // t-tile 0..255
    int b  = (id >> 8) & (BATCH - 1);      // batch
    int dg = id >> 10;                     // d-group

    int d  = dg * DCH + threadIdx.x;
    int t0 = tt * NT;

    const float* xd = x + ((size_t)b * SEQ) * DIM + d;
    const float* ld = last + (size_t)CLEN * DIM + d;  // ld[r*DIM] valid for r in [-512,-1]
    const float* fd = filt + d;

    float acc[NT];
#pragma unroll
    for (int i = 0; i < NT; ++i) acc[i] = 0.f;

    float wA[NT], wB[NT], fA[NT], fB[NT];

    // Prologue: block 0 (hi of chunk 0) and its taps.
    LOAD_BLK(wA, 0)
    LOAD_FR(fA, 0)

#pragma unroll 1
    for (int wp = 0; wp < NBLK; wp += 2) {
        // ---- chunk wp: hi=wA, lo=wB ----
        LOAD_BLK(wB, wp + 1)                 // wp+1 <= 31: rows >= t0-496 >= -496, in range
        { int kb = (wp + 1) * NT; LOAD_FR(fB, kb) }   // kb <= 496, in range
        UFMA(fA, wA)                         // 136 FMAs hide wB/fB latency
        LFMA(fA, wB)
        // ---- chunk wp+1: hi=wB, lo=wA ----
        LOAD_BLK(wA, wp + 2)                 // block 32: rows >= t0-512 >= -512, edge-legal
        { int kb = (wp + 2) * NT;
          if (kb > CLEN - NT) kb = CLEN - NT;  // row 512 would be OOB; values unused
          LOAD_FR(fA, kb) }
        UFMA(fB, wB)
        LFMA(fB, wA)
    }

    float* ob = out + ((size_t)b * SEQ) * DIM + d;
#pragma unroll
    for (int i = 0; i < NT; ++i)
        ob[(size_t)(t0 + i) * DIM] = acc[i];
}

extern "C" void kernel_launch(void* const* d_in, const int* in_sizes, int n_in,
                              void* d_out, int out_size, void* d_ws, size_t ws_size,
                              hipStream_t stream) {
    const float* x    = (const float*)d_in[0];
    const float* last = (const float*)d_in[1];
    const float* filt = (const float*)d_in[2];
    float* out        = (float*)d_out;

    const int nblocks = BATCH * (DIM / DCH) * (SEQ / NT);  // 4*4*256 = 4096
    cconv_fir<<<dim3(nblocks), dim3(DCH), 0, stream>>>(x, last, filt, out);
}

// Round 8
// 274.299 us; speedup vs baseline: 3.4444x; 1.5555x over previous
//
#include <hip/hip_runtime.h>

// Causal depthwise FIR conv, 512 taps, fp32.
// v7: block = one (batch, channel-pair). x-window staged once into ROW-PADDED
//     LDS (136B stride: conflict-free AND linear read offsets — round-7's XOR
//     swizzle was wrong because XOR doesn't commute with +8m read offsets).
//     Filter via wave-uniform s_load into SGPRs; float2 accs -> v_pk_fma_f32.

typedef float f32x2 __attribute__((ext_vector_type(2)));

constexpr int CLEN  = 512;
constexpr int SEQ   = 4096;
constexpr int DIM   = 1024;
constexpr int BATCH = 4;

constexpr int NT      = 16;            // outputs per thread
constexpr int THREADS = 256;           // one block covers SEQ = 256*16
constexpr int NW      = SEQ + CLEN;    // 4608 window entries (f32x2 each)
constexpr int NCH     = CLEN / NT;     // 32 tap-chunks
constexpr int LDS_BYTES = (NW / 16) * 136;   // 288 rows * (128B + 8B pad)

// entry e lives at byte 8*e + 8*(e>>4)  (row stride 136B)
#define ENT_ADDR(e) (((e) << 3) + (((e) >> 4) << 3))

// Wave-uniform filter chunk -> SGPRs (s_load): index depends only on block id.
#define LOADF(dst, kb)                                            \
  _Pragma("unroll")                                               \
  for (int j = 0; j < NT; ++j)                                    \
    dst[j] = fp2[(size_t)((kb) + j) * (DIM / 2)];

// Window block cblk: 16 f32x2 entries starting at L = CLEN + t0 - 16*cblk.
// L is 16-aligned, so all 16 entries sit in one padded row: base + 8m.
#define LDSRD(w, cblk)                                            \
  {                                                               \
    int L_ = CLEN + t0 - NT * (cblk);                             \
    const char* p_ = ldsb + ENT_ADDR(L_);                         \
    _Pragma("unroll")                                             \
    for (int m = 0; m < NT; ++m)                                  \
      w[m] = *(const f32x2*)(p_ + 8 * m);                         \
  }

// Upper triangle: taps j, outputs i>=j, resident hi block.
#define UFMA(f, hi)                                               \
  _Pragma("unroll")                                               \
  for (int j = 0; j < NT; ++j)                                    \
    _Pragma("unroll")                                             \
    for (int i = j; i < NT; ++i)                                  \
      acc[i] = __builtin_elementwise_fma(f[j], hi[i - j], acc[i]);

// Lower triangle: outputs i<j, freshly loaded lo block.
#define LFMA(f, lo)                                               \
  _Pragma("unroll")                                               \
  for (int j = 1; j < NT; ++j)                                    \
    _Pragma("unroll")                                             \
    for (int i = 0; i < j; ++i)                                   \
      acc[i] = __builtin_elementwise_fma(f[j], lo[NT + i - j], acc[i]);

__global__ __launch_bounds__(THREADS, 2) void cconv_fir(
    const float* __restrict__ x,      // [BATCH][SEQ][DIM]
    const float* __restrict__ last,   // [CLEN][DIM]
    const float* __restrict__ filt,   // [CLEN][DIM]
    float* __restrict__ out)          // [BATCH][SEQ][DIM]
{
    __shared__ __attribute__((aligned(16))) char ldsb[LDS_BYTES];

    // Bijective XCD swizzle (2048 % 8 == 0). id = b*512 + d2: consecutive d2
    // share HBM 64B lines -> keep them on the same XCD for L2 merge.
    int bid = blockIdx.x;
    int id  = (bid & 7) * (int)(gridDim.x >> 3) + (bid >> 3);
    int d2  = id & (DIM / 2 - 1);      // channel-pair 0..511
    int b   = id >> 9;                 // batch

    const int tid = threadIdx.x;

    // ---- stage window: entry j = X2(j - CLEN), j in [0, 4608) ----
    const float* xrow = x + (size_t)b * SEQ * DIM + 2 * d2;
    const float* lrow = last + 2 * d2;
#pragma unroll
    for (int it = 0; it < NW / THREADS; ++it) {
        int j = tid + it * THREADS;
        const float* src = (j < CLEN) ? (lrow + (size_t)j * DIM)
                                      : (xrow + (size_t)(j - CLEN) * DIM);
        f32x2 v = *(const f32x2*)src;
        *(f32x2*)(ldsb + ENT_ADDR(j)) = v;
    }
    __syncthreads();

    const f32x2* fp2 = (const f32x2*)filt + d2;   // uniform: row k at fp2[k*512]
    int t0 = tid * NT;

    f32x2 acc[NT];
    f32x2 z = {0.f, 0.f};
#pragma unroll
    for (int i = 0; i < NT; ++i) acc[i] = z;

    f32x2 wA[NT], wB[NT], fc[NT], fn[NT];

    LDSRD(wA, 0)
    LOADF(fc, 0)

#pragma unroll 1
    for (int c = 0; c < NCH; c += 2) {
        // chunk c: hi=wA, lo=wB
        LDSRD(wB, c + 1)
        LOADF(fn, (c + 1) * NT)
        UFMA(fc, wA)
        LFMA(fc, wB)
        // chunk c+1: hi=wB, lo=wA (block c+2; block 32 = entries t0..t0+15, valid)
        LDSRD(wA, c + 2)
        { int kb = (c + 2) * NT;
          if (kb > CLEN - NT) kb = CLEN - NT;   // avoid OOB s_load; values unused
          LOADF(fc, kb) }
        UFMA(fn, wB)
        LFMA(fn, wA)
    }

    float* orow = out + (size_t)b * SEQ * DIM + (size_t)t0 * DIM + 2 * d2;
#pragma unroll
    for (int i = 0; i < NT; ++i)
        *(f32x2*)(orow + (size_t)i * DIM) = acc[i];
}

extern "C" void kernel_launch(void* const* d_in, const int* in_sizes, int n_in,
                              void* d_out, int out_size, void* d_ws, size_t ws_size,
                              hipStream_t stream) {
    const float* x    = (const float*)d_in[0];
    const float* last = (const float*)d_in[1];
    const float* filt = (const float*)d_in[2];
    float* out        = (float*)d_out;

    const int nblocks = BATCH * (DIM / 2);   // 4 * 512 = 2048
    cconv_fir<<<dim3(nblocks), dim3(THREADS), 0, stream>>>(x, last, filt, out);
}

// Round 9
// 225.395 us; speedup vs baseline: 4.1917x; 1.2170x over previous
//
#include <hip/hip_runtime.h>
#include <hip/hip_bf16.h>

// Causal depthwise FIR conv, 512 taps — bf16 MFMA Toeplitz formulation.
// out[b,t,d] = sum_k f[k,d] X(t-k);  C-tile: t = T0 + i + 16 s, i,s in [0,16).
// A[i,j] = fhat[32c + i - j] (filter Toeplitz, static per channel, 17 frags in regs)
// B[j,s] = X(T0 - 32c + 16 s + j) (window, bf16 in padded LDS)
// 17 chunks c=0..16 cover taps [0,512) exactly once per row.

typedef float  f32x4  __attribute__((ext_vector_type(4)));
typedef short  bf16x8 __attribute__((ext_vector_type(8)));
typedef short  bf16x4 __attribute__((ext_vector_type(4)));

constexpr int CLEN  = 512;
constexpr int SEQ   = 4096;
constexpr int DIM   = 1024;
constexpr int BATCH = 4;

constexpr int NW    = CLEN + SEQ + 32;          // 4640 window entries (+32 guard)
constexpr int WINB  = 2 * NW + 8 * (NW / 16);   // padded bytes: 2m + 8*(m>>4) -> 11600
constexpr int FLEN  = 560;                      // fhat[-31..528] zero-padded
constexpr int FPAD0 = 4 * WINB;                 // 46400
constexpr int LDSSZ = FPAD0 + 4 * 2 * FLEN;     // 50880 B

__device__ __forceinline__ int wbyte(int m) { return 2 * m + 8 * (m >> 4); }

__global__ __launch_bounds__(256, 2) void cconv_mfma(
    const float* __restrict__ x,      // [BATCH][SEQ][DIM]
    const float* __restrict__ last,   // [CLEN][DIM]
    const float* __restrict__ filt,   // [CLEN][DIM]
    float* __restrict__ out)          // [BATCH][SEQ][DIM]
{
    __shared__ __attribute__((aligned(16))) char lds[LDSSZ];

    // Bijective XCD swizzle (1024 % 8 == 0); consecutive ids share x/out lines.
    int bid = blockIdx.x;
    int id  = (bid & 7) * (int)(gridDim.x >> 3) + (bid >> 3);
    int bg  = id & 255;                // channel-group
    int b   = id >> 8;                 // batch
    int d0  = bg * 4;

    const int tid = threadIdx.x;

    // ---- stage window: entry m = X(m - CLEN) for 4 channels, bf16, padded ----
    const float* xb = x + (size_t)b * SEQ * DIM;
#pragma unroll 1
    for (int it = 0; it < 19; ++it) {
        int m = tid + it * 256;
        if (m < NW) {
            f32x4 v = {0.f, 0.f, 0.f, 0.f};
            if (m < CLEN)           v = *(const f32x4*)(last + (size_t)m * DIM + d0);
            else if (m < CLEN + SEQ) v = *(const f32x4*)(xb + (size_t)(m - CLEN) * DIM + d0);
            int byt = wbyte(m);
#pragma unroll
            for (int ch = 0; ch < 4; ++ch)
                *(__hip_bfloat16*)(lds + ch * WINB + byt) = __float2bfloat16(v[ch]);
        }
    }
    // ---- stage fhat: fp[q] = fhat[q-31], zero outside [0,512) ----
#pragma unroll 1
    for (int it = 0; it < 3; ++it) {
        int q = tid + it * 256;
        if (q < FLEN) {
            int v = q - 31;
            f32x4 f = {0.f, 0.f, 0.f, 0.f};
            if (v >= 0 && v < CLEN) f = *(const f32x4*)(filt + (size_t)v * DIM + d0);
#pragma unroll
            for (int ch = 0; ch < 4; ++ch)
                *(__hip_bfloat16*)(lds + FPAD0 + ch * 2 * FLEN + 2 * q) = __float2bfloat16(f[ch]);
        }
    }
    __syncthreads();

    const int lane = tid & 63, wid = tid >> 6;
    const int i = lane & 15, g = lane >> 4;   // i = A-row & B-col (s); g = k-group

    // ---- build 17 static A fragments: elem e -> fhat[32c + i - 8g - e] ----
    const short* fp = (const short*)(lds + FPAD0 + wid * 2 * FLEN);
    bf16x8 afr[17];
#pragma unroll
    for (int c = 0; c <= 16; ++c) {
        int qb = 32 * c + 31 + i - 8 * g;
        bf16x8 a;
#pragma unroll
        for (int e = 0; e < 8; ++e) a[e] = fp[qb - e];
        afr[c] = a;
    }

    // B lane byte offset: entry m0 = WB + 16 s + 8 g, byte = wbyte(m0) (s == i)
    const int laneB = 40 * i + 16 * g + 8 * (g >> 1);
    const char* win = lds + wid * WINB;
    float* outb = out + (size_t)b * SEQ * DIM + (d0 + wid);

#pragma unroll 1
    for (int jt = 0; jt < 16; ++jt) {
        const int T0 = jt * 256;
        f32x4 acc0 = {0.f, 0.f, 0.f, 0.f};
        f32x4 acc1 = {0.f, 0.f, 0.f, 0.f};
#pragma unroll
        for (int c = 0; c <= 16; ++c) {
            int WB = CLEN + T0 - 32 * c;              // multiple of 32, >= 0
            const char* p = win + (2 * WB + 8 * (WB >> 4)) + laneB;
            bf16x4 b0 = *(const bf16x4*)(p);
            bf16x4 b1 = *(const bf16x4*)(p + 8);
            bf16x8 bb = __builtin_shufflevector(b0, b1, 0, 1, 2, 3, 4, 5, 6, 7);
            if (c & 1)
                acc1 = __builtin_amdgcn_mfma_f32_16x16x32_bf16(afr[c], bb, acc1, 0, 0, 0);
            else
                acc0 = __builtin_amdgcn_mfma_f32_16x16x32_bf16(afr[c], bb, acc0, 0, 0, 0);
        }
        // C lane layout: col = lane&15 (= s), row = 4g + e;  t = T0 + row + 16 s
        const int tb = T0 + 4 * g + 16 * i;
#pragma unroll
        for (int e = 0; e < 4; ++e)
            outb[(size_t)(tb + e) * DIM] = acc0[e] + acc1[e];
    }
}

extern "C" void kernel_launch(void* const* d_in, const int* in_sizes, int n_in,
                              void* d_out, int out_size, void* d_ws, size_t ws_size,
                              hipStream_t stream) {
    const float* x    = (const float*)d_in[0];
    const float* last = (const float*)d_in[1];
    const float* filt = (const float*)d_in[2];
    float* out        = (float*)d_out;

    const int nblocks = BATCH * (DIM / 4);   // 4 * 256 = 1024
    cconv_mfma<<<dim3(nblocks), dim3(256), 0, stream>>>(x, last, filt, out);
}